// Round 3
// baseline (314.805 us; speedup 1.0000x reference)
//
#include <hip/hip_runtime.h>

// Unfold: x[B=32, C=64, H=64, W=64] fp32, KH=KW=3, stride=1
// out[b][c*9 + i*3 + j][ho*62 + wo] = x[b][c][ho+i][wo+j]; out [32, 576, 3844].
//
// One block per (b,c). Stage the 16 KB channel in LDS (natural layout, no
// swizzle), then each thread handles one output element-PAIR l=2t for ALL
// 9 kernel offsets at once:
//   - l even & 62 even -> pair never wraps an Ho row -> single (ho,wo),
//     single tile address a = ho*64 + wo per iteration.
//   - 18 inputs = tile[a + i*64 + j + e] -> 12 distinct ds_read_b32 with
//     compile-time immediate offsets (CSE'd), zero per-read addr math.
//   - consecutive lanes -> consecutive tile addrs -> stride-1, conflict-free.
//   - 9 float2 stores, lanes contiguous -> 512B per wave store issue.

#define B 32
#define C 64
#define H 64
#define W 64
#define HO 62
#define WO 62
#define L (HO * WO)   // 3844
#define L2 (L / 2)    // 1922
#define KK 9

__global__ __launch_bounds__(256, 8) void unfold_kernel(
    const float* __restrict__ x, float* __restrict__ out) {
    __shared__ float tile[H * W];  // 16 KB, natural layout

    const int c   = blockIdx.x;   // 0..63
    const int b   = blockIdx.y;   // 0..31
    const int tid = threadIdx.x;  // 0..255

    // ---- Stage channel (b,c): 1024 float4, lanes contiguous. ----
    const float4* __restrict__ src =
        (const float4*)(x + (((size_t)(b * C + c)) << 12));
    float4* __restrict__ t4 = (float4*)tile;
#pragma unroll
    for (int r = 0; r < 4; ++r) {
        t4[tid + r * 256] = src[tid + r * 256];
    }
    __syncthreads();

    // ---- Emit: each iteration = 1 element-pair x 9 k-rows. ----
    float2* __restrict__ dst2 =
        (float2*)out + (size_t)(b * C + c) * KK * L2;

    for (int pe = tid; pe < L2; pe += 256) {
        const int l  = pe * 2;
        const int ho = l / WO;            // magic-mul div (WO=62 const)
        const int wo = l - ho * WO;       // even, <= 60 -> pair stays in-row
        const int a  = ho * W + wo;

#pragma unroll
        for (int i = 0; i < 3; ++i) {
#pragma unroll
            for (int j = 0; j < 3; ++j) {
                float2 v;
                v.x = tile[a + i * W + j];      // immediate-offset ds_read
                v.y = tile[a + i * W + j + 1];  // CSE with neighbor j
                dst2[(i * 3 + j) * L2 + pe] = v;
            }
        }
    }
}

extern "C" void kernel_launch(void* const* d_in, const int* in_sizes, int n_in,
                              void* d_out, int out_size, void* d_ws, size_t ws_size,
                              hipStream_t stream) {
    const float* x = (const float*)d_in[0];
    float* out = (float*)d_out;

    dim3 block(256, 1, 1);
    dim3 grid(C, B, 1);  // 2048 blocks = 8/CU, all resident (16KB LDS, <=64 VGPR)
    unfold_kernel<<<grid, block, 0, stream>>>(x, out);
}